// Round 14
// baseline (221.118 us; speedup 1.0000x reference)
//
#include <hip/hip_runtime.h>

// Problem constants
#define BATCH 2
#define SEQ   2048
#define NH    16
#define DK    64
#define DM    1024
#define MROWS 4096        // BATCH*SEQ
#define NX    4194304     // MROWS*DM elems
#define NW    1048576     // DM*DM elems

typedef __attribute__((ext_vector_type(8))) short bf16x8;
typedef __attribute__((ext_vector_type(4))) short bf16x4;
typedef __attribute__((ext_vector_type(4))) float f32x4;
typedef __attribute__((ext_vector_type(4))) unsigned short us16x4;
typedef __attribute__((ext_vector_type(2))) unsigned int u32x2;

// Device pass has the _1k builtin; host pass only needs to parse.
#if __has_builtin(__builtin_amdgcn_mfma_f32_16x16x16bf16_1k)
#define MFMA16(a, b, c) __builtin_amdgcn_mfma_f32_16x16x16bf16_1k(a, b, c, 0, 0, 0)
#else
#define MFMA16(a, b, c) (c)
#endif

__device__ __forceinline__ unsigned short f2bf(float f) {
  unsigned int u = __builtin_bit_cast(unsigned int, f);
  u += 0x7FFFu + ((u >> 16) & 1u);
  return (unsigned short)(u >> 16);
}

// pack two fp32 -> two truncated bf16 in one dword: {hi>>16 : lo>>16}
__device__ __forceinline__ unsigned int pkbf(float hi, float lo) {
#if __has_builtin(__builtin_amdgcn_perm)
  return __builtin_amdgcn_perm(__builtin_bit_cast(unsigned int, hi),
                               __builtin_bit_cast(unsigned int, lo), 0x07060302u);
#else
  return (__builtin_bit_cast(unsigned int, hi) & 0xffff0000u) |
         (__builtin_bit_cast(unsigned int, lo) >> 16);
#endif
}

__device__ __forceinline__ void g2l16(void* lds, const void* g) {
  __builtin_amdgcn_global_load_lds(
      (const __attribute__((address_space(1))) void*)g,
      (__attribute__((address_space(3))) void*)lds, 16, 0, 0);
}

// ---------------- cast fp32 -> bf16 (7 arrays concatenated) ----------------
__global__ __launch_bounds__(256) void cast_all(
    const float* __restrict__ q, const float* __restrict__ k, const float* __restrict__ v,
    const float* __restrict__ wq, const float* __restrict__ wk,
    const float* __restrict__ wv, const float* __restrict__ wo,
    unsigned short* __restrict__ dst) {
  size_t e = ((size_t)blockIdx.x * 256 + threadIdx.x) * 4;
  const float* src;
  if      (e < (size_t)NX)        src = q  + e;
  else if (e < (size_t)2*NX)      src = k  + (e - (size_t)NX);
  else if (e < (size_t)3*NX)      src = v  + (e - (size_t)2*NX);
  else if (e < (size_t)3*NX+NW)   src = wq + (e - (size_t)3*NX);
  else if (e < (size_t)3*NX+2*NW) src = wk + (e - (size_t)3*NX-NW);
  else if (e < (size_t)3*NX+3*NW) src = wv + (e - (size_t)3*NX-2*NW);
  else                            src = wo + (e - (size_t)3*NX-3*NW);
  float4 f = *(const float4*)src;
  us16x4 o;
  o[0] = f2bf(f.x); o[1] = f2bf(f.y); o[2] = f2bf(f.z); o[3] = f2bf(f.w);
  *(us16x4*)(dst + e) = o;
}

// ---------------- GEMM: C = X @ W^T (+bias), BMx128 tile, 1-deep pipeline ----------------
// R14: R6 structure + intra-row XOR LDS swizzle (LAYOUT fix, not a schedule
// graft). Mechanism: 64 B row stride -> a quarter-wave's 16 lanes (fixed quad)
// read banks {0,16} only = 8-way conflict on every ds_read_b128 (m136: 2.94x;
// R5 counters: 3.1M conflict-cycles on this read structure). Fix (same species
// as gemm_o's verified swizzle + the guide's +89% attn fix): k-group gs stored
// at slot gs ^ ((r>>1)&3) via pre-swizzled GLOBAL column (linear LDS dest,
// g2l16-safe), read with matching XOR -> 8 distinct banks per quarter-wave =
// 2-way = free. Stage coalescing preserved (permutation within 64 B segment).
// Schedule untouched (this loop rejected 3 schedule grafts).
// MODE 0: z in {0,1,2}: z<2 -> bf16 scatter to [B,H,S,DK] (z==0 scaled);
//         z==2 -> V^T bf16 scatter to [B,H,DK,S] (packed us16x4 along s).
template <int MODE, int BM>
__global__ __launch_bounds__(256) void gemm_bt(
    const unsigned short* __restrict__ Xbase, const unsigned short* __restrict__ Wbase,
    const float* __restrict__ b0, const float* __restrict__ b1, const float* __restrict__ b2,
    unsigned short* __restrict__ qkv_dst, float* __restrict__ fout, float qscale) {
  constexpr int IM = BM / 32;           // 16-row frags per wave
  constexpr int ASHOTS = (BM * 32) / 2048;
  const int tid  = threadIdx.x;
  const int lane = tid & 63;
  const int w    = tid >> 6;
  const int wm   = w >> 1, wn = w & 1;
  const int x15  = lane & 15, quad = lane >> 4;
  const int row0 = blockIdx.x * BM;
  const int col0 = blockIdx.y * 128;
  const int z    = blockIdx.z;

  const unsigned short* A  = Xbase + (size_t)z * NX;
  const unsigned short* Wp = Wbase + (size_t)z * NW;
  const float* bias = (MODE == 0) ? (z == 0 ? b0 : (z == 1 ? b1 : b2)) : b0;
  const float zs = (MODE == 0 && z == 0) ? qscale : 1.0f;

  __shared__ __align__(16) unsigned short At[2][BM * 32];
  __shared__ __align__(16) unsigned short Bt[2][128 * 32];

  f32x4 acc[IM][4] = {};

  // stage: linear LDS dest; global column pre-swizzled so LDS slot gs holds
  // k-group gs ^ ((r>>1)&3).
  auto stage = [&](int buf, int kt) {
#pragma unroll
    for (int j = 0; j < ASHOTS; ++j) {
      int e = (j * 256 + tid) * 8;
      int r = e >> 5, gs = (e >> 3) & 3;
      int c = (gs ^ ((r >> 1) & 3)) * 8;
      g2l16(&At[buf][e], A + (size_t)(row0 + r) * DM + kt + c);
    }
#pragma unroll
    for (int j = 0; j < 2; ++j) {
      int e = (j * 256 + tid) * 8;
      int r = e >> 5, gs = (e >> 3) & 3;
      int c = (gs ^ ((r >> 1) & 3)) * 8;
      g2l16(&Bt[buf][e], Wp + (size_t)(col0 + r) * DM + kt + c);
    }
  };

  stage(0, 0);
  for (int it = 0; it < DM / 32; ++it) {
    const int cur = it & 1;
    __syncthreads();                 // drains prefetch issued last iter; guards buf reuse
    if (it + 1 < DM / 32) stage(cur ^ 1, (it + 1) * 32);
    bf16x8 af[IM], bfv[4];
#pragma unroll
    for (int i = 0; i < IM; ++i) {
      const int r = wm * (BM / 2) + i * 16 + x15;
      af[i] = *(const bf16x8*)&At[cur][r * 32 + ((quad ^ ((r >> 1) & 3)) << 3)];
    }
#pragma unroll
    for (int jn = 0; jn < 4; ++jn) {
      const int r = wn * 64 + jn * 16 + x15;
      bfv[jn] = *(const bf16x8*)&Bt[cur][r * 32 + ((quad ^ ((r >> 1) & 3)) << 3)];
    }
#pragma unroll
    for (int i = 0; i < IM; ++i)
#pragma unroll
      for (int jn = 0; jn < 4; ++jn)
        acc[i][jn] = __builtin_amdgcn_mfma_f32_16x16x32_bf16(af[i], bfv[jn], acc[i][jn], 0, 0, 0);
  }

  // epilogue: C[row=(quad*4+r), col=x15] within each 16x16 tile
#pragma unroll
  for (int jn = 0; jn < 4; ++jn) {
    const int n = col0 + wn * 64 + jn * 16 + x15;
    const float bv = bias[n];
#pragma unroll
    for (int i = 0; i < IM; ++i) {
      const int m0 = row0 + wm * (BM / 2) + i * 16 + quad * 4;
      if (MODE == 0 && z == 2) {
        us16x4 pk;
#pragma unroll
        for (int r = 0; r < 4; ++r) pk[r] = f2bf(acc[i][jn][r] + bv);
        const int b = m0 >> 11, s = m0 & 2047;
        const int h = n >> 6,  dk = n & 63;
        *(us16x4*)&qkv_dst[(size_t)2 * NX + (((size_t)(b * NH + h) * DK + dk) << 11) + s] = pk;
      } else {
#pragma unroll
        for (int r = 0; r < 4; ++r) {
          const int m = m0 + r;
          float val = (acc[i][jn][r] + bv) * zs;
          if (MODE == 0) {
            const int b = m >> 11, s = m & 2047;
            const int h = n >> 6,  dk = n & 63;
            qkv_dst[(size_t)z * NX + (((size_t)(b * NH + h) * SEQ + s) << 6) + dk] = f2bf(val);
          } else {
            fout[(size_t)m * DM + n] = val;
          }
        }
      }
    }
  }
}

// ---------------- output projection: out = AO @ Wo^T + bo, fp32 ----------------
// R12-verified. 2-phase skeleton, BK=64 (16 iters), XOR-swizzled LDS via
// pre-swizzled global source + swizzled b128 reads. Tile 64x128, 4 waves 2x2;
// 16 MFMA + 12 ds_read_b128 per iter.
__global__ __launch_bounds__(256) void gemm_o(
    const unsigned short* __restrict__ A, const unsigned short* __restrict__ Wp,
    const float* __restrict__ bias, float* __restrict__ fout) {
  const int tid  = threadIdx.x;
  const int lane = tid & 63;
  const int w    = tid >> 6;
  const int wm   = w >> 1, wn = w & 1;
  const int x15  = lane & 15, quad = lane >> 4;
  const int row0 = blockIdx.x * 64;
  const int col0 = blockIdx.y * 128;

  __shared__ __align__(16) unsigned short At[2][64 * 64];    // 16 KB
  __shared__ __align__(16) unsigned short Bt[2][128 * 64];   // 32 KB

  f32x4 acc[2][4] = {};

  // stage: linear LDS dest (slot L = r*64 + gs*8), pre-swizzled global col
  // c = (gs ^ (r&7))*8 so that read-side XOR recovers k-order.
  auto stage = [&](int buf, int kt) {
#pragma unroll
    for (int j = 0; j < 2; ++j) {                  // At: 4096 elems, 2 shots
      int e = (j * 256 + tid) * 8;
      int r = e >> 6, gs = (e >> 3) & 7;
      int c = (gs ^ (r & 7)) * 8;
      g2l16(&At[buf][e], A + (size_t)(row0 + r) * DM + kt + c);
    }
#pragma unroll
    for (int j = 0; j < 4; ++j) {                  // Bt: 8192 elems, 4 shots
      int e = (j * 256 + tid) * 8;
      int r = e >> 6, gs = (e >> 3) & 7;
      int c = (gs ^ (r & 7)) * 8;
      g2l16(&Bt[buf][e], Wp + (size_t)(col0 + r) * DM + kt + c);
    }
  };

  stage(0, 0);
  for (int it = 0; it < DM / 64; ++it) {
    const int cur = it & 1;
    __syncthreads();                 // drains prefetch issued last iter; guards buf reuse
    if (it + 1 < DM / 64) stage(cur ^ 1, (it + 1) * 64);
    bf16x8 af[2][2], bfv[4][2];
#pragma unroll
    for (int i = 0; i < 2; ++i) {
      const int r = wm * 32 + i * 16 + x15;
#pragma unroll
      for (int kk = 0; kk < 2; ++kk) {
        const int gs = (kk * 4 + quad) ^ (r & 7);
        af[i][kk] = *(const bf16x8*)&At[cur][(r << 6) + (gs << 3)];
      }
    }
#pragma unroll
    for (int jn = 0; jn < 4; ++jn) {
      const int r = wn * 64 + jn * 16 + x15;
#pragma unroll
      for (int kk = 0; kk < 2; ++kk) {
        const int gs = (kk * 4 + quad) ^ (r & 7);
        bfv[jn][kk] = *(const bf16x8*)&Bt[cur][(r << 6) + (gs << 3)];
      }
    }
#pragma unroll
    for (int kk = 0; kk < 2; ++kk)
#pragma unroll
      for (int i = 0; i < 2; ++i)
#pragma unroll
        for (int jn = 0; jn < 4; ++jn)
          acc[i][jn] = __builtin_amdgcn_mfma_f32_16x16x32_bf16(af[i][kk], bfv[jn][kk], acc[i][jn], 0, 0, 0);
  }

  // epilogue: C[row=(quad*4+r), col=x15] within each 16x16 tile
#pragma unroll
  for (int jn = 0; jn < 4; ++jn) {
    const int n = col0 + wn * 64 + jn * 16 + x15;
    const float bv = bias[n];
#pragma unroll
    for (int i = 0; i < 2; ++i) {
      const int m0 = row0 + wm * 32 + i * 16 + quad * 4;
#pragma unroll
      for (int r = 0; r < 4; ++r)
        fout[(size_t)(m0 + r) * DM + n] = acc[i][jn][r] + bv;
    }
  }
}

// ---------------- flash attention, q-tile 128, 2x2 wave split, counted-vmcnt ----------------
// R14: reverted to the R11-verified form (50.8 us). R13's phase-split was
// undone by the compiler (VGPR stayed 88) and cost +2.2 us -- intra-wave ILP
// cannot be forced at HIP source level without order-pinning that regresses.
// This kernel is at its structural floor for this decomposition (R1-R13
// forensics: TLP, LDS traffic, barriers, L2 locality, KVBLK, phase-split all
// exhausted). DO NOT TOUCH.
__global__ __launch_bounds__(256, 2) void attn(
    const unsigned short* __restrict__ Qb, const unsigned short* __restrict__ Kb,
    const unsigned short* __restrict__ VTb, unsigned short* __restrict__ AO) {
  const int tid  = threadIdx.x;
  const int lane = tid & 63;
  const int w    = tid >> 6;
  const int wq   = w & 1;        // q-half owner
  const int ws   = w >> 1;       // s-half owner
  const int x15  = lane & 15, quad = lane >> 4;
  // bijective XCD swizzle: 512 blocks = 8 XCDs x 64; each XCD owns 4 (b,h)
  const int lin = (int)(blockIdx.x | (blockIdx.y << 4) | (blockIdx.z << 8));
  const int swz = ((lin & 7) << 6) | (lin >> 3);
  const int qt = swz & 15;          // 16
  const int h  = (swz >> 4) & 15;   // 16
  const int b  = swz >> 8;          // 2
  const size_t bh = ((size_t)(b * NH + h)) * SEQ * DK;
  const unsigned short* Q  = Qb  + bh;
  const unsigned short* K  = Kb  + bh;
  const unsigned short* VT = VTb + bh;   // [64 d][2048 s]
  const int q0 = qt * 128;               // block covers q0..q0+127

  // 3 K bufs + 3 V bufs (48 KB) overlaid with epilogue O-reduction buffer (34.8 KB)
  __shared__ __align__(16) unsigned short smem[3 * 4096 * 2];
  unsigned short* Kl = smem;             // [3][64*64] swizzled
  unsigned short* Vl = smem + 12288;     // [3][64*64] swizzled
  float* Ored = (float*)smem;            // [2 ws][64 q][68] post-loop overlay
  __shared__ float lbuf[2][4][128];      // [ws][quad][q-local]

  // Q fragments (scaled by 1/8*log2e at projection): wave's 4 16-row groups
  bf16x8 qf[4][2];
#pragma unroll
  for (int qgi = 0; qgi < 4; ++qgi)
#pragma unroll
    for (int ks = 0; ks < 2; ++ks)
      qf[qgi][ks] = *(const bf16x8*)&Q[(size_t)(q0 + wq * 64 + qgi * 16 + x15) * DK + ks * 32 + quad * 8];

  f32x4 po[4][4] = {};
  float pol[4] = {0.f, 0.f, 0.f, 0.f};

  // staging maps (swizzled): K slot(s,dg)=s*8+(dg^(s&7)); V slot(d,sg)=d*8+(sg^(d&7))
  const int sK0 = tid >> 3,          sK1 = (tid + 256) >> 3;
  const int dgK0 = (tid & 7) ^ (sK0 & 7), dgK1 = (tid & 7) ^ (sK1 & 7);

  auto stageKV = [&](int buf, int s0) {
    const int bo = buf * 4096;
    g2l16(&Kl[bo + tid * 8],         K + (size_t)(s0 + sK0) * DK + dgK0 * 8);
    g2l16(&Kl[bo + (tid + 256) * 8], K + (size_t)(s0 + sK1) * DK + dgK1 * 8);
    g2l16(&Vl[bo + tid * 8],         VT + (size_t)sK0 * SEQ + s0 + dgK0 * 8);
    g2l16(&Vl[bo + (tid + 256) * 8], VT + (size_t)sK1 * SEQ + s0 + dgK1 * 8);
  };

  int ca = 0, cb = 1, cc = 2;   // rotating buffer indices (uniform)
  stageKV(0, 0);
  stageKV(1, 64);
  for (int i = 0; i < SEQ / 64; ++i) {
    // retire stage(i)'s 4 loads; stage(i+1)'s 4 stay in flight
    asm volatile("s_waitcnt vmcnt(4)" ::: "memory");
    __builtin_amdgcn_sched_barrier(0);
    __builtin_amdgcn_s_barrier();      // all waves' slices of buf ca are in LDS
    stageKV(cc, ((i + 2) * 64) & (SEQ - 1));   // wrapped tail stages harmless
    const int ko = ca * 4096;

    // this wave's K fragments: sh = ws*2 + shi
    bf16x8 kf[2][2];
#pragma unroll
    for (int shi = 0; shi < 2; ++shi) {
      const int sh = ws * 2 + shi;
      const int kbase = (sh * 16 + x15) * 8;
      kf[shi][0] = *(const bf16x8*)&Kl[ko + (kbase + ((0 + quad) ^ (x15 & 7))) * 8];
      kf[shi][1] = *(const bf16x8*)&Kl[ko + (kbase + ((4 + quad) ^ (x15 & 7))) * 8];
    }
    // this wave's V fragments
    bf16x4 vf[2][4];
#pragma unroll
    for (int shi = 0; shi < 2; ++shi)
#pragma unroll
      for (int nt = 0; nt < 4; ++nt) {
        const int d = nt * 16 + x15;
        const int sg = ((ws * 2 + shi) * 2 + (quad >> 1)) ^ (d & 7);
        vf[shi][nt] = *(const bf16x4*)&Vl[ko + (d * 8 + sg) * 8 + (quad & 1) * 4];
      }

#pragma unroll
    for (int shi = 0; shi < 2; ++shi) {
#pragma unroll
      for (int qgi = 0; qgi < 4; ++qgi) {
        f32x4 sacc = {};
        sacc = __builtin_amdgcn_mfma_f32_16x16x32_bf16(kf[shi][0], qf[qgi][0], sacc, 0, 0, 0);
        sacc = __builtin_amdgcn_mfma_f32_16x16x32_bf16(kf[shi][1], qf[qgi][1], sacc, 0, 0, 0);
        float p0 = __builtin_amdgcn_exp2f(sacc[0]);
        float p1 = __builtin_amdgcn_exp2f(sacc[1]);
        float p2 = __builtin_amdgcn_exp2f(sacc[2]);
        float p3 = __builtin_amdgcn_exp2f(sacc[3]);
        pol[qgi] += (p0 + p1) + (p2 + p3);     // in-lane row-sum partial (quad's 4 s)
        u32x2 uu;
        uu[0] = pkbf(p1, p0);
        uu[1] = pkbf(p3, p2);
        bf16x4 pf = __builtin_bit_cast(bf16x4, uu);
#pragma unroll
        for (int nt = 0; nt < 4; ++nt)
          po[qgi][nt] = MFMA16(vf[shi][nt], pf, po[qgi][nt]);
      }
    }
    int t = ca; ca = cb; cb = cc; cc = t;
  }

  // ---- epilogue: cross-quad l reduce + cross-ws O reduce via LDS ----
#pragma unroll
  for (int qgi = 0; qgi < 4; ++qgi)
    lbuf[ws][quad][wq * 64 + qgi * 16 + x15] = pol[qgi];
  __syncthreads();   // full drain (incl. wrapped stages); safe to overlay Ored

  const int qq = tid >> 2;          // 0..63 (q-local within the round's half)
  const int d0 = (tid & 3) * 16;    // 0,16,32,48
#pragma unroll
  for (int rw = 0; rw < 2; ++rw) {
    if (wq == rw) {
      // write O^T partial: element (d = nt*16+quad*4+r, q = qgi*16+x15)
#pragma unroll
      for (int qgi = 0; qgi < 4; ++qgi)
#pragma unroll
        for (int nt = 0; nt < 4; ++nt)
          *(f32x4*)&Ored[(ws * 64 + qgi * 16 + x15) * 68 + nt * 16 + quad * 4] = po[qgi][nt];
    }
    __syncthreads();
    float ls = 0.f;
#pragma unroll
    for (int w2 = 0; w2 < 2; ++w2)
#pragma unroll
      for (int qd = 0; qd < 4; ++qd)
        ls += lbuf[w2][qd][rw * 64 + qq];
    const float inv = 1.0f / ls;
    const size_t orow = ((size_t)(b * SEQ + q0 + rw * 64 + qq)) * DM + h * DK + d0;
#pragma unroll
    for (int c = 0; c < 4; ++c) {
      f32x4 sa = *(const f32x4*)&Ored[(0 * 64 + qq) * 68 + d0 + c * 4];
      f32x4 sb = *(const f32x4*)&Ored[(1 * 64 + qq) * 68 + d0 + c * 4];
      us16x4 pk;
#pragma unroll
      for (int r = 0; r < 4; ++r) pk[r] = f2bf((sa[r] + sb[r]) * inv);
      *(us16x4*)&AO[orow + c * 4] = pk;
    }
    __syncthreads();  // before round 1 overwrites Ored
  }
}

extern "C" void kernel_launch(void* const* d_in, const int* in_sizes, int n_in,
                              void* d_out, int out_size, void* d_ws, size_t ws_size,
                              hipStream_t stream) {
  const float* q  = (const float*)d_in[0];
  const float* k  = (const float*)d_in[1];
  const float* v  = (const float*)d_in[2];
  const float* wq = (const float*)d_in[3];
  const float* bq = (const float*)d_in[4];
  const float* wk = (const float*)d_in[5];
  const float* bk = (const float*)d_in[6];
  const float* wv = (const float*)d_in[7];
  const float* bv = (const float*)d_in[8];
  const float* wo = (const float*)d_in[9];
  const float* bo = (const float*)d_in[10];
  float* out = (float*)d_out;

  unsigned short* ws = (unsigned short*)d_ws;
  unsigned short* Xq = ws;                               // 3*NX of X
  unsigned short* Wb = ws + (size_t)3 * NX;              // 4*NW of W
  unsigned short* Qb = ws + (size_t)3 * NX + 4 * NW;     // Q,K [B,H,S,DK]; V^T [B,H,DK,S]
  unsigned short* AO = Qb + (size_t)3 * NX;              // NX attn out

  // scale folded into Q: (1/sqrt(DK)) * log2(e)
  const float qscale = 0.125f * 1.4426950408889634f;

  cast_all<<<16384, 256, 0, stream>>>(q, k, v, wq, wk, wv, wo, ws);
  gemm_bt<0, 128><<<dim3(32, 8, 3), 256, 0, stream>>>(Xq, Wb, bq, bk, bv, Qb, nullptr, qscale);
  attn<<<dim3(16, 16, 2), 256, 0, stream>>>(Qb, Qb + (size_t)NX, Qb + (size_t)2 * NX, AO);
  gemm_o<<<dim3(64, 8), 256, 0, stream>>>(AO, Wb + (size_t)3 * NW, bo, out);
}

// Round 16
// 215.918 us; speedup vs baseline: 1.0241x; 1.0241x over previous
//
#include <hip/hip_runtime.h>

// Problem constants
#define BATCH 2
#define SEQ   2048
#define NH    16
#define DK    64
#define DM    1024
#define MROWS 4096        // BATCH*SEQ
#define NX    4194304     // MROWS*DM elems
#define NW    1048576     // DM*DM elems

typedef __attribute__((ext_vector_type(8))) short bf16x8;
typedef __attribute__((ext_vector_type(4))) short bf16x4;
typedef __attribute__((ext_vector_type(4))) float f32x4;
typedef __attribute__((ext_vector_type(4))) unsigned short us16x4;
typedef __attribute__((ext_vector_type(2))) unsigned int u32x2;

// Device pass has the _1k builtin; host pass only needs to parse.
#if __has_builtin(__builtin_amdgcn_mfma_f32_16x16x16bf16_1k)
#define MFMA16(a, b, c) __builtin_amdgcn_mfma_f32_16x16x16bf16_1k(a, b, c, 0, 0, 0)
#else
#define MFMA16(a, b, c) (c)
#endif

__device__ __forceinline__ unsigned short f2bf(float f) {
  unsigned int u = __builtin_bit_cast(unsigned int, f);
  u += 0x7FFFu + ((u >> 16) & 1u);
  return (unsigned short)(u >> 16);
}

// pack two fp32 -> two truncated bf16 in one dword: {hi>>16 : lo>>16}
__device__ __forceinline__ unsigned int pkbf(float hi, float lo) {
#if __has_builtin(__builtin_amdgcn_perm)
  return __builtin_amdgcn_perm(__builtin_bit_cast(unsigned int, hi),
                               __builtin_bit_cast(unsigned int, lo), 0x07060302u);
#else
  return (__builtin_bit_cast(unsigned int, hi) & 0xffff0000u) |
         (__builtin_bit_cast(unsigned int, lo) >> 16);
#endif
}

__device__ __forceinline__ void g2l16(void* lds, const void* g) {
  __builtin_amdgcn_global_load_lds(
      (const __attribute__((address_space(1))) void*)g,
      (__attribute__((address_space(3))) void*)lds, 16, 0, 0);
}

// ---------------- cast fp32 -> bf16 (7 arrays concatenated) ----------------
__global__ __launch_bounds__(256) void cast_all(
    const float* __restrict__ q, const float* __restrict__ k, const float* __restrict__ v,
    const float* __restrict__ wq, const float* __restrict__ wk,
    const float* __restrict__ wv, const float* __restrict__ wo,
    unsigned short* __restrict__ dst) {
  size_t e = ((size_t)blockIdx.x * 256 + threadIdx.x) * 4;
  const float* src;
  if      (e < (size_t)NX)        src = q  + e;
  else if (e < (size_t)2*NX)      src = k  + (e - (size_t)NX);
  else if (e < (size_t)3*NX)      src = v  + (e - (size_t)2*NX);
  else if (e < (size_t)3*NX+NW)   src = wq + (e - (size_t)3*NX);
  else if (e < (size_t)3*NX+2*NW) src = wk + (e - (size_t)3*NX-NW);
  else if (e < (size_t)3*NX+3*NW) src = wv + (e - (size_t)3*NX-2*NW);
  else                            src = wo + (e - (size_t)3*NX-3*NW);
  float4 f = *(const float4*)src;
  us16x4 o;
  o[0] = f2bf(f.x); o[1] = f2bf(f.y); o[2] = f2bf(f.z); o[3] = f2bf(f.w);
  *(us16x4*)(dst + e) = o;
}

// ---------------- GEMM: C = X @ W^T (+bias), BMx128 tile, 1-deep pipeline ----------------
// R6-known-good kernel, byte-identical. This 2-phase loop has rejected FOUR
// grafts (T4 counted-vmcnt -30%, sched_barrier, operand-swap epilogue -20%,
// R14 bank swizzle neutral-negative: conflicts hidden under the barrier drain,
// T2 regime-gate). This form is the local optimum. Do not touch.
// MODE 0: z in {0,1,2}: z<2 -> bf16 scatter to [B,H,S,DK] (z==0 scaled);
//         z==2 -> V^T bf16 scatter to [B,H,DK,S] (packed us16x4 along s).
template <int MODE, int BM>
__global__ __launch_bounds__(256) void gemm_bt(
    const unsigned short* __restrict__ Xbase, const unsigned short* __restrict__ Wbase,
    const float* __restrict__ b0, const float* __restrict__ b1, const float* __restrict__ b2,
    unsigned short* __restrict__ qkv_dst, float* __restrict__ fout, float qscale) {
  constexpr int IM = BM / 32;           // 16-row frags per wave
  constexpr int ASHOTS = (BM * 32) / 2048;
  const int tid  = threadIdx.x;
  const int lane = tid & 63;
  const int w    = tid >> 6;
  const int wm   = w >> 1, wn = w & 1;
  const int x15  = lane & 15, quad = lane >> 4;
  const int row0 = blockIdx.x * BM;
  const int col0 = blockIdx.y * 128;
  const int z    = blockIdx.z;

  const unsigned short* A  = Xbase + (size_t)z * NX;
  const unsigned short* Wp = Wbase + (size_t)z * NW;
  const float* bias = (MODE == 0) ? (z == 0 ? b0 : (z == 1 ? b1 : b2)) : b0;
  const float zs = (MODE == 0 && z == 0) ? qscale : 1.0f;

  __shared__ __align__(16) unsigned short At[2][BM * 32];
  __shared__ __align__(16) unsigned short Bt[2][128 * 32];

  f32x4 acc[IM][4] = {};

  auto stage = [&](int buf, int kt) {
#pragma unroll
    for (int j = 0; j < ASHOTS; ++j) {
      int e = (j * 256 + tid) * 8;
      int r = e >> 5, c = e & 31;
      g2l16(&At[buf][e], A + (size_t)(row0 + r) * DM + kt + c);
    }
#pragma unroll
    for (int j = 0; j < 2; ++j) {
      int e = (j * 256 + tid) * 8;
      int r = e >> 5, c = e & 31;
      g2l16(&Bt[buf][e], Wp + (size_t)(col0 + r) * DM + kt + c);
    }
  };

  stage(0, 0);
  for (int it = 0; it < DM / 32; ++it) {
    const int cur = it & 1;
    __syncthreads();                 // drains prefetch issued last iter; guards buf reuse
    if (it + 1 < DM / 32) stage(cur ^ 1, (it + 1) * 32);
    bf16x8 af[IM], bfv[4];
#pragma unroll
    for (int i = 0; i < IM; ++i)
      af[i] = *(const bf16x8*)&At[cur][(wm * (BM / 2) + i * 16 + x15) * 32 + quad * 8];
#pragma unroll
    for (int jn = 0; jn < 4; ++jn)
      bfv[jn] = *(const bf16x8*)&Bt[cur][(wn * 64 + jn * 16 + x15) * 32 + quad * 8];
#pragma unroll
    for (int i = 0; i < IM; ++i)
#pragma unroll
      for (int jn = 0; jn < 4; ++jn)
        acc[i][jn] = __builtin_amdgcn_mfma_f32_16x16x32_bf16(af[i], bfv[jn], acc[i][jn], 0, 0, 0);
  }

  // epilogue: C[row=(quad*4+r), col=x15] within each 16x16 tile
#pragma unroll
  for (int jn = 0; jn < 4; ++jn) {
    const int n = col0 + wn * 64 + jn * 16 + x15;
    const float bv = bias[n];
#pragma unroll
    for (int i = 0; i < IM; ++i) {
      const int m0 = row0 + wm * (BM / 2) + i * 16 + quad * 4;
      if (MODE == 0 && z == 2) {
        us16x4 pk;
#pragma unroll
        for (int r = 0; r < 4; ++r) pk[r] = f2bf(acc[i][jn][r] + bv);
        const int b = m0 >> 11, s = m0 & 2047;
        const int h = n >> 6,  dk = n & 63;
        *(us16x4*)&qkv_dst[(size_t)2 * NX + (((size_t)(b * NH + h) * DK + dk) << 11) + s] = pk;
      } else {
#pragma unroll
        for (int r = 0; r < 4; ++r) {
          const int m = m0 + r;
          float val = (acc[i][jn][r] + bv) * zs;
          if (MODE == 0) {
            const int b = m >> 11, s = m & 2047;
            const int h = n >> 6,  dk = n & 63;
            qkv_dst[(size_t)z * NX + (((size_t)(b * NH + h) * SEQ + s) << 6) + dk] = f2bf(val);
          } else {
            fout[(size_t)m * DM + n] = val;
          }
        }
      }
    }
  }
}

// ---------------- output projection: out = AO @ Wo^T + bo, fp32 ----------------
// R12-verified. 2-phase skeleton, BK=64 (16 iters), XOR-swizzled LDS via
// pre-swizzled global source + swizzled b128 reads. Tile 64x128, 4 waves 2x2;
// 16 MFMA + 12 ds_read_b128 per iter.
__global__ __launch_bounds__(256) void gemm_o(
    const unsigned short* __restrict__ A, const unsigned short* __restrict__ Wp,
    const float* __restrict__ bias, float* __restrict__ fout) {
  const int tid  = threadIdx.x;
  const int lane = tid & 63;
  const int w    = tid >> 6;
  const int wm   = w >> 1, wn = w & 1;
  const int x15  = lane & 15, quad = lane >> 4;
  const int row0 = blockIdx.x * 64;
  const int col0 = blockIdx.y * 128;

  __shared__ __align__(16) unsigned short At[2][64 * 64];    // 16 KB
  __shared__ __align__(16) unsigned short Bt[2][128 * 64];   // 32 KB

  f32x4 acc[2][4] = {};

  // stage: linear LDS dest (slot L = r*64 + gs*8), pre-swizzled global col
  // c = (gs ^ (r&7))*8 so that read-side XOR recovers k-order.
  auto stage = [&](int buf, int kt) {
#pragma unroll
    for (int j = 0; j < 2; ++j) {                  // At: 4096 elems, 2 shots
      int e = (j * 256 + tid) * 8;
      int r = e >> 6, gs = (e >> 3) & 7;
      int c = (gs ^ (r & 7)) * 8;
      g2l16(&At[buf][e], A + (size_t)(row0 + r) * DM + kt + c);
    }
#pragma unroll
    for (int j = 0; j < 4; ++j) {                  // Bt: 8192 elems, 4 shots
      int e = (j * 256 + tid) * 8;
      int r = e >> 6, gs = (e >> 3) & 7;
      int c = (gs ^ (r & 7)) * 8;
      g2l16(&Bt[buf][e], Wp + (size_t)(col0 + r) * DM + kt + c);
    }
  };

  stage(0, 0);
  for (int it = 0; it < DM / 64; ++it) {
    const int cur = it & 1;
    __syncthreads();                 // drains prefetch issued last iter; guards buf reuse
    if (it + 1 < DM / 64) stage(cur ^ 1, (it + 1) * 64);
    bf16x8 af[2][2], bfv[4][2];
#pragma unroll
    for (int i = 0; i < 2; ++i) {
      const int r = wm * 32 + i * 16 + x15;
#pragma unroll
      for (int kk = 0; kk < 2; ++kk) {
        const int gs = (kk * 4 + quad) ^ (r & 7);
        af[i][kk] = *(const bf16x8*)&At[cur][(r << 6) + (gs << 3)];
      }
    }
#pragma unroll
    for (int jn = 0; jn < 4; ++jn) {
      const int r = wn * 64 + jn * 16 + x15;
#pragma unroll
      for (int kk = 0; kk < 2; ++kk) {
        const int gs = (kk * 4 + quad) ^ (r & 7);
        bfv[jn][kk] = *(const bf16x8*)&Bt[cur][(r << 6) + (gs << 3)];
      }
    }
#pragma unroll
    for (int kk = 0; kk < 2; ++kk)
#pragma unroll
      for (int i = 0; i < 2; ++i)
#pragma unroll
        for (int jn = 0; jn < 4; ++jn)
          acc[i][jn] = __builtin_amdgcn_mfma_f32_16x16x32_bf16(af[i][kk], bfv[jn][kk], acc[i][jn], 0, 0, 0);
  }

  // epilogue: C[row=(quad*4+r), col=x15] within each 16x16 tile
#pragma unroll
  for (int jn = 0; jn < 4; ++jn) {
    const int n = col0 + wn * 64 + jn * 16 + x15;
    const float bv = bias[n];
#pragma unroll
    for (int i = 0; i < 2; ++i) {
      const int m0 = row0 + wm * 32 + i * 16 + quad * 4;
#pragma unroll
      for (int r = 0; r < 4; ++r)
        fout[(size_t)(m0 + r) * DM + n] = acc[i][jn][r] + bv;
    }
  }
}

// ---------------- flash attention, q-tile 128, 2x2 wave split, counted-vmcnt ----------------
// R11/R12/R14-verified (50.8-51.3 us). 3-buffer K/V, 2-deep prefetch, per-iter
// s_waitcnt vmcnt(4) + raw s_barrier; loads stay in flight across barriers.
// Geometry: 512 blocks (2/CU exact), wave (wq,ws) owns q-half wq*64..+63 and
// s-half ws*32..+31. l-row-sum via VALU; epilogue cross-(quad,ws) reduce
// through LDS overlay. XCD swizzle: 512 = 8 XCDs x 64. At its structural floor
// (R1-R13 forensics: TLP, LDS traffic, barriers, L2 locality, KVBLK,
// phase-split all exhausted). DO NOT TOUCH.
__global__ __launch_bounds__(256, 2) void attn(
    const unsigned short* __restrict__ Qb, const unsigned short* __restrict__ Kb,
    const unsigned short* __restrict__ VTb, unsigned short* __restrict__ AO) {
  const int tid  = threadIdx.x;
  const int lane = tid & 63;
  const int w    = tid >> 6;
  const int wq   = w & 1;        // q-half owner
  const int ws   = w >> 1;       // s-half owner
  const int x15  = lane & 15, quad = lane >> 4;
  // bijective XCD swizzle: 512 blocks = 8 XCDs x 64; each XCD owns 4 (b,h)
  const int lin = (int)(blockIdx.x | (blockIdx.y << 4) | (blockIdx.z << 8));
  const int swz = ((lin & 7) << 6) | (lin >> 3);
  const int qt = swz & 15;          // 16
  const int h  = (swz >> 4) & 15;   // 16
  const int b  = swz >> 8;          // 2
  const size_t bh = ((size_t)(b * NH + h)) * SEQ * DK;
  const unsigned short* Q  = Qb  + bh;
  const unsigned short* K  = Kb  + bh;
  const unsigned short* VT = VTb + bh;   // [64 d][2048 s]
  const int q0 = qt * 128;               // block covers q0..q0+127

  // 3 K bufs + 3 V bufs (48 KB) overlaid with epilogue O-reduction buffer (34.8 KB)
  __shared__ __align__(16) unsigned short smem[3 * 4096 * 2];
  unsigned short* Kl = smem;             // [3][64*64] swizzled
  unsigned short* Vl = smem + 12288;     // [3][64*64] swizzled
  float* Ored = (float*)smem;            // [2 ws][64 q][68] post-loop overlay
  __shared__ float lbuf[2][4][128];      // [ws][quad][q-local]

  // Q fragments (scaled by 1/8*log2e at projection): wave's 4 16-row groups
  bf16x8 qf[4][2];
#pragma unroll
  for (int qgi = 0; qgi < 4; ++qgi)
#pragma unroll
    for (int ks = 0; ks < 2; ++ks)
      qf[qgi][ks] = *(const bf16x8*)&Q[(size_t)(q0 + wq * 64 + qgi * 16 + x15) * DK + ks * 32 + quad * 8];

  f32x4 po[4][4] = {};
  float pol[4] = {0.f, 0.f, 0.f, 0.f};

  // staging maps (swizzled): K slot(s,dg)=s*8+(dg^(s&7)); V slot(d,sg)=d*8+(sg^(d&7))
  const int sK0 = tid >> 3,          sK1 = (tid + 256) >> 3;
  const int dgK0 = (tid & 7) ^ (sK0 & 7), dgK1 = (tid & 7) ^ (sK1 & 7);

  auto stageKV = [&](int buf, int s0) {
    const int bo = buf * 4096;
    g2l16(&Kl[bo + tid * 8],         K + (size_t)(s0 + sK0) * DK + dgK0 * 8);
    g2l16(&Kl[bo + (tid + 256) * 8], K + (size_t)(s0 + sK1) * DK + dgK1 * 8);
    g2l16(&Vl[bo + tid * 8],         VT + (size_t)sK0 * SEQ + s0 + dgK0 * 8);
    g2l16(&Vl[bo + (tid + 256) * 8], VT + (size_t)sK1 * SEQ + s0 + dgK1 * 8);
  };

  int ca = 0, cb = 1, cc = 2;   // rotating buffer indices (uniform)
  stageKV(0, 0);
  stageKV(1, 64);
  for (int i = 0; i < SEQ / 64; ++i) {
    // retire stage(i)'s 4 loads; stage(i+1)'s 4 stay in flight
    asm volatile("s_waitcnt vmcnt(4)" ::: "memory");
    __builtin_amdgcn_sched_barrier(0);
    __builtin_amdgcn_s_barrier();      // all waves' slices of buf ca are in LDS
    stageKV(cc, ((i + 2) * 64) & (SEQ - 1));   // wrapped tail stages harmless
    const int ko = ca * 4096;

    // this wave's K fragments: sh = ws*2 + shi
    bf16x8 kf[2][2];
#pragma unroll
    for (int shi = 0; shi < 2; ++shi) {
      const int sh = ws * 2 + shi;
      const int kbase = (sh * 16 + x15) * 8;
      kf[shi][0] = *(const bf16x8*)&Kl[ko + (kbase + ((0 + quad) ^ (x15 & 7))) * 8];
      kf[shi][1] = *(const bf16x8*)&Kl[ko + (kbase + ((4 + quad) ^ (x15 & 7))) * 8];
    }
    // this wave's V fragments
    bf16x4 vf[2][4];
#pragma unroll
    for (int shi = 0; shi < 2; ++shi)
#pragma unroll
      for (int nt = 0; nt < 4; ++nt) {
        const int d = nt * 16 + x15;
        const int sg = ((ws * 2 + shi) * 2 + (quad >> 1)) ^ (d & 7);
        vf[shi][nt] = *(const bf16x4*)&Vl[ko + (d * 8 + sg) * 8 + (quad & 1) * 4];
      }

#pragma unroll
    for (int shi = 0; shi < 2; ++shi) {
#pragma unroll
      for (int qgi = 0; qgi < 4; ++qgi) {
        f32x4 sacc = {};
        sacc = __builtin_amdgcn_mfma_f32_16x16x32_bf16(kf[shi][0], qf[qgi][0], sacc, 0, 0, 0);
        sacc = __builtin_amdgcn_mfma_f32_16x16x32_bf16(kf[shi][1], qf[qgi][1], sacc, 0, 0, 0);
        float p0 = __builtin_amdgcn_exp2f(sacc[0]);
        float p1 = __builtin_amdgcn_exp2f(sacc[1]);
        float p2 = __builtin_amdgcn_exp2f(sacc[2]);
        float p3 = __builtin_amdgcn_exp2f(sacc[3]);
        pol[qgi] += (p0 + p1) + (p2 + p3);     // in-lane row-sum partial (quad's 4 s)
        u32x2 uu;
        uu[0] = pkbf(p1, p0);
        uu[1] = pkbf(p3, p2);
        bf16x4 pf = __builtin_bit_cast(bf16x4, uu);
#pragma unroll
        for (int nt = 0; nt < 4; ++nt)
          po[qgi][nt] = MFMA16(vf[shi][nt], pf, po[qgi][nt]);
      }
    }
    int t = ca; ca = cb; cb = cc; cc = t;
  }

  // ---- epilogue: cross-quad l reduce + cross-ws O reduce via LDS ----
#pragma unroll
  for (int qgi = 0; qgi < 4; ++qgi)
    lbuf[ws][quad][wq * 64 + qgi * 16 + x15] = pol[qgi];
  __syncthreads();   // full drain (incl. wrapped stages); safe to overlay Ored

  const int qq = tid >> 2;          // 0..63 (q-local within the round's half)
  const int d0 = (tid & 3) * 16;    // 0,16,32,48
#pragma unroll
  for (int rw = 0; rw < 2; ++rw) {
    if (wq == rw) {
      // write O^T partial: element (d = nt*16+quad*4+r, q = qgi*16+x15)
#pragma unroll
      for (int qgi = 0; qgi < 4; ++qgi)
#pragma unroll
        for (int nt = 0; nt < 4; ++nt)
          *(f32x4*)&Ored[(ws * 64 + qgi * 16 + x15) * 68 + nt * 16 + quad * 4] = po[qgi][nt];
    }
    __syncthreads();
    float ls = 0.f;
#pragma unroll
    for (int w2 = 0; w2 < 2; ++w2)
#pragma unroll
      for (int qd = 0; qd < 4; ++qd)
        ls += lbuf[w2][qd][rw * 64 + qq];
    const float inv = 1.0f / ls;
    const size_t orow = ((size_t)(b * SEQ + q0 + rw * 64 + qq)) * DM + h * DK + d0;
#pragma unroll
    for (int c = 0; c < 4; ++c) {
      f32x4 sa = *(const f32x4*)&Ored[(0 * 64 + qq) * 68 + d0 + c * 4];
      f32x4 sb = *(const f32x4*)&Ored[(1 * 64 + qq) * 68 + d0 + c * 4];
      us16x4 pk;
#pragma unroll
      for (int r = 0; r < 4; ++r) pk[r] = f2bf((sa[r] + sb[r]) * inv);
      *(us16x4*)&AO[orow + c * 4] = pk;
    }
    __syncthreads();  // before round 1 overwrites Ored
  }
}

extern "C" void kernel_launch(void* const* d_in, const int* in_sizes, int n_in,
                              void* d_out, int out_size, void* d_ws, size_t ws_size,
                              hipStream_t stream) {
  const float* q  = (const float*)d_in[0];
  const float* k  = (const float*)d_in[1];
  const float* v  = (const float*)d_in[2];
  const float* wq = (const float*)d_in[3];
  const float* bq = (const float*)d_in[4];
  const float* wk = (const float*)d_in[5];
  const float* bk = (const float*)d_in[6];
  const float* wv = (const float*)d_in[7];
  const float* bv = (const float*)d_in[8];
  const float* wo = (const float*)d_in[9];
  const float* bo = (const float*)d_in[10];
  float* out = (float*)d_out;

  unsigned short* ws = (unsigned short*)d_ws;
  unsigned short* Xq = ws;                               // 3*NX of X
  unsigned short* Wb = ws + (size_t)3 * NX;              // 4*NW of W
  unsigned short* Qb = ws + (size_t)3 * NX + 4 * NW;     // Q,K [B,H,S,DK]; V^T [B,H,DK,S]
  unsigned short* AO = Qb + (size_t)3 * NX;              // NX attn out

  // scale folded into Q: (1/sqrt(DK)) * log2(e)
  const float qscale = 0.125f * 1.4426950408889634f;

  cast_all<<<16384, 256, 0, stream>>>(q, k, v, wq, wk, wv, wo, ws);
  gemm_bt<0, 128><<<dim3(32, 8, 3), 256, 0, stream>>>(Xq, Wb, bq, bk, bv, Qb, nullptr, qscale);
  attn<<<dim3(16, 16, 2), 256, 0, stream>>>(Qb, Qb + (size_t)NX, Qb + (size_t)2 * NX, AO);
  gemm_o<<<dim3(64, 8), 256, 0, stream>>>(AO, Wb + (size_t)3 * NW, bo, out);
}